// Round 3
// baseline (361.639 us; speedup 1.0000x reference)
//
#include <hip/hip_runtime.h>
#include <hip/hip_bf16.h>

typedef __attribute__((ext_vector_type(8))) short bf16x8;
typedef __attribute__((ext_vector_type(4))) float f32x4;
typedef unsigned short u16;
typedef unsigned int u32;

#define EPS 1e-5f
#define CIN 96
#define HD 576
#define HW 3136
#define WCOLS 56
#define NB 32
#define LDK 104   // padded LDS K-stride (elements): 208B rows -> 16B aligned b128 ops, conflict-free (8 writes/bank = wave64 minimum)

__device__ __forceinline__ u16 f2bf(float f) {
  u32 u = __builtin_bit_cast(u32, f);
  u32 r = u + 0x7fffu + ((u >> 16) & 1u);   // RNE
  return (u16)(r >> 16);
}
__device__ __forceinline__ float bf2f(u16 h) {
  return __builtin_bit_cast(float, (u32)h << 16);
}

// ---------------- kernel 0: weight conversion + BN folding ----------------
__global__ __launch_bounds__(256) void prep_kernel(
    const float* __restrict__ w1, const float* __restrict__ w2,
    const float* __restrict__ g1, const float* __restrict__ b1,
    const float* __restrict__ m1, const float* __restrict__ v1,
    const float* __restrict__ gdw, const float* __restrict__ bdw,
    const float* __restrict__ mdw, const float* __restrict__ vdw,
    const float* __restrict__ g2, const float* __restrict__ b2,
    const float* __restrict__ m2, const float* __restrict__ v2,
    u16* __restrict__ w1b, u16* __restrict__ w2b, float* __restrict__ bn)
{
  int i = blockIdx.x * 256 + threadIdx.x;
  if (i < HD * CIN) {
    w1b[i] = f2bf(w1[i]);
    w2b[i] = f2bf(w2[i]);
  }
  if (i < HD) {
    float s = g1[i] * rsqrtf(v1[i] + EPS);
    bn[i] = s;
    bn[HD + i] = b1[i] - m1[i] * s;
    float sd = gdw[i] * rsqrtf(vdw[i] + EPS);
    bn[2 * HD + i] = sd;
    bn[3 * HD + i] = bdw[i] - mdw[i] * sd;
  }
  if (i < CIN) {
    float s2 = g2[i] * rsqrtf(v2[i] + EPS);
    bn[4 * HD + i] = s2;
    bn[4 * HD + CIN + i] = b2[i] - m2[i] * s2;
  }
}

// ---------------- kernel 1: expand 1x1 (GEMM) + BN + ReLU -> bf16 h -------
// per batch: out[o,p] = sum_c w1[o,c] * x[c,p];  M=576, K=96, N=3136
// block: 256 thr (4 waves, 2x2), tile 64(M) x 64(N), K staged whole (96)
// blockIdx: x = strip (7 tiles of 64 px), y = M-block (9), z = batch (32)
__global__ __launch_bounds__(256) void expand_kernel(
    const float* __restrict__ x, const u16* __restrict__ w1b,
    const float* __restrict__ bn, u16* __restrict__ h)
{
  __shared__ __align__(16) u16 A[64 * LDK];    // w1 tile [64 M][96 K]
  __shared__ __align__(16) u16 Bt[64 * LDK];   // x tile transposed [64 px][96 K]
  __shared__ float s1[64], sh1[64];

  const int tid = threadIdx.x;
  const int b  = blockIdx.z;
  const int o0 = blockIdx.y * 64;
  const int l  = tid & 63;
  const int wv = tid >> 6;
  const int wm = wv >> 1, wn = wv & 1;
  const int ar = l & 15;
  const int kb = (l >> 4) * 8;

  // stage A once: 64 rows x 96 cols, b128
  for (int i = tid; i < 64 * (CIN / 8); i += 256) {
    int r  = i / (CIN / 8);
    int c8 = (i - r * (CIN / 8)) * 8;
    *(uint4*)&A[r * LDK + c8] = *(const uint4*)&w1b[(o0 + r) * CIN + c8];
  }
  if (tid < 64) {
    s1[tid]  = bn[o0 + tid];
    sh1[tid] = bn[HD + o0 + tid];
  }

  const float* xb = x + (size_t)b * CIN * HW;
  u16* hb = h + (size_t)b * HD * HW;

  for (int t = 0; t < 7; ++t) {
    const int p0 = (blockIdx.x * 7 + t) * 64;
    __syncthreads();   // protects Bt against previous iteration readers (and A/s1 on t=0)
    // stage Bt: thread gathers 8 channels for one px -> one b128 write
    // (coalesced dword loads across lanes; conflict-free LDS writes)
    for (int i = tid; i < 768; i += 256) {
      int px = i & 63;
      int g  = i >> 6;          // 0..11, channel block g*8
      const float* xp = xb + (size_t)(g * 8) * HW + p0 + px;
      bf16x8 pk;
#pragma unroll
      for (int j = 0; j < 8; ++j) pk[j] = (short)f2bf(xp[(size_t)j * HW]);
      *(bf16x8*)&Bt[px * LDK + g * 8] = pk;
    }
    __syncthreads();

    f32x4 acc[2][2] = {};
#pragma unroll
    for (int ks = 0; ks < 3; ++ks) {
      bf16x8 af0 = *(const bf16x8*)&A[(wm * 32 +      ar) * LDK + ks * 32 + kb];
      bf16x8 af1 = *(const bf16x8*)&A[(wm * 32 + 16 + ar) * LDK + ks * 32 + kb];
      bf16x8 bg0 = *(const bf16x8*)&Bt[(wn * 32 +      ar) * LDK + ks * 32 + kb];
      bf16x8 bg1 = *(const bf16x8*)&Bt[(wn * 32 + 16 + ar) * LDK + ks * 32 + kb];
      acc[0][0] = __builtin_amdgcn_mfma_f32_16x16x32_bf16(af0, bg0, acc[0][0], 0, 0, 0);
      acc[0][1] = __builtin_amdgcn_mfma_f32_16x16x32_bf16(af0, bg1, acc[0][1], 0, 0, 0);
      acc[1][0] = __builtin_amdgcn_mfma_f32_16x16x32_bf16(af1, bg0, acc[1][0], 0, 0, 0);
      acc[1][1] = __builtin_amdgcn_mfma_f32_16x16x32_bf16(af1, bg1, acc[1][1], 0, 0, 0);
    }

    // epilogue: BN + ReLU, write bf16
#pragma unroll
    for (int mt = 0; mt < 2; ++mt) {
#pragma unroll
      for (int i = 0; i < 4; ++i) {
        int oc = wm * 32 + mt * 16 + (l >> 4) * 4 + i;   // local channel 0..63
        float sc = s1[oc], sh = sh1[oc];
        size_t orow = (size_t)(o0 + oc) * HW;
#pragma unroll
        for (int nt = 0; nt < 2; ++nt) {
          int p = p0 + wn * 32 + nt * 16 + (l & 15);
          float v = fmaxf(acc[mt][nt][i] * sc + sh, 0.f);
          hb[orow + p] = f2bf(v);
        }
      }
    }
  }
}

// ---------------- kernel 2: depthwise 3x3 + BN + ReLU ---------------------
// 4 outputs/thread along x. block: 256 thr = 16 col-groups (14 used) x 16 rows
// grid: (4 row-strips, 576 ch, 32 b)
__global__ __launch_bounds__(256) void dw_kernel(
    const u16* __restrict__ h, const float* __restrict__ wdw,
    const float* __restrict__ bn, u16* __restrict__ h2)
{
  const int tx  = threadIdx.x & 15;   // col group
  const int ty  = threadIdx.x >> 4;   // row within strip
  const int row = blockIdx.x * 16 + ty;
  const int ch  = blockIdx.y;
  const int b   = blockIdx.z;
  if (tx >= 14 || row >= WCOLS) return;
  const int c0 = tx * 4;

  const size_t base = ((size_t)b * HD + ch) * HW;
  const u16* hp = h + base;

  float wk[9];
#pragma unroll
  for (int k = 0; k < 9; ++k) wk[k] = wdw[ch * 9 + k];
  const float sc = bn[2 * HD + ch], sh = bn[3 * HD + ch];

  float acc[4] = {0.f, 0.f, 0.f, 0.f};
#pragma unroll
  for (int dy = 0; dy < 3; ++dy) {
    int rr = row + dy - 1;
    if ((unsigned)rr >= WCOLS) continue;
    const u16* rp = hp + rr * WCOLS;
    // window w[0..7] = cols c0-2 .. c0+5 via 4 aligned u32 loads
    float w[8];
#pragma unroll
    for (int k = 0; k < 4; ++k) {
      int cbase = c0 - 2 + 2 * k;
      if (cbase >= 0) {   // false only for k=0 at c0==0 (cols -2,-1)
        u32 pr = *(const u32*)(rp + cbase);
        w[2 * k]     = bf2f((u16)pr);
        w[2 * k + 1] = bf2f((u16)(pr >> 16));
      } else {
        w[2 * k] = 0.f; w[2 * k + 1] = 0.f;
      }
    }
    if (c0 + 4 >= WCOLS) w[6] = 0.f;   // col 56 (right edge); w[7] never used
#pragma unroll
    for (int j = 0; j < 4; ++j)
#pragma unroll
      for (int dx = 0; dx < 3; ++dx)
        acc[j] += wk[dy * 3 + dx] * w[j + dx + 1];
  }

  u16 ov[4];
#pragma unroll
  for (int j = 0; j < 4; ++j) ov[j] = f2bf(fmaxf(acc[j] * sc + sh, 0.f));
  u32 lo = (u32)ov[0] | ((u32)ov[1] << 16);
  u32 hi = (u32)ov[2] | ((u32)ov[3] << 16);
  uint2 st; st.x = lo; st.y = hi;
  *(uint2*)(h2 + base + row * WCOLS + c0) = st;
}

// ---------------- kernel 3: project 1x1 (GEMM) + BN + residual ------------
// per batch: out[c,p] = sum_o w2[c,o] * h2[o,p];  M=96, K=576, N=3136
// block: 256 thr (4 waves, each 96x16 cols), tile 96 x 64, K in 6 chunks of 96
__global__ __launch_bounds__(256) void proj_kernel(
    const u16* __restrict__ h2, const u16* __restrict__ w2b,
    const float* __restrict__ bn, const float* __restrict__ x,
    float* __restrict__ out)
{
  __shared__ __align__(16) u16 A[CIN * LDK];   // w2 chunk [96 M][96 K]
  __shared__ __align__(16) u16 Bt[64 * LDK];   // h2 chunk transposed [64 px][96 K]

  const int tid = threadIdx.x;
  const int b  = blockIdx.y;
  const int p0 = blockIdx.x * 64;
  const int l  = tid & 63;
  const int wv = tid >> 6;
  const int ar = l & 15;
  const int kb = (l >> 4) * 8;

  const u16* h2b = h2 + (size_t)b * HD * HW;

  f32x4 acc[6] = {};
  for (int kc = 0; kc < 6; ++kc) {
    const int k0 = kc * 96;
    __syncthreads();
    // A chunk: 96 x 96, b128
    for (int i = tid; i < CIN * 12; i += 256) {
      int r  = i / 12;
      int c8 = (i - r * 12) * 8;
      *(uint4*)&A[r * LDK + c8] = *(const uint4*)&w2b[r * HD + k0 + c8];
    }
    // B chunk transposed: thread gathers 8 k for one px -> one b128 write
    for (int i = tid; i < 768; i += 256) {
      int px = i & 63;
      int g  = i >> 6;          // 0..11
      const u16* sp = h2b + (size_t)(k0 + g * 8) * HW + p0 + px;
      bf16x8 pk;
#pragma unroll
      for (int j = 0; j < 8; ++j) pk[j] = (short)sp[(size_t)j * HW];
      *(bf16x8*)&Bt[px * LDK + g * 8] = pk;
    }
    __syncthreads();
#pragma unroll
    for (int ks = 0; ks < 3; ++ks) {
      bf16x8 bfr = *(const bf16x8*)&Bt[(wv * 16 + ar) * LDK + ks * 32 + kb];
#pragma unroll
      for (int mt = 0; mt < 6; ++mt) {
        bf16x8 afr = *(const bf16x8*)&A[(mt * 16 + ar) * LDK + ks * 32 + kb];
        acc[mt] = __builtin_amdgcn_mfma_f32_16x16x32_bf16(afr, bfr, acc[mt], 0, 0, 0);
      }
    }
  }

  // epilogue: BN (no ReLU) + residual, fp32 out
  const float* xb = x + (size_t)b * CIN * HW;
  float* ob = out + (size_t)b * CIN * HW;
  const int p = p0 + wv * 16 + (l & 15);
#pragma unroll
  for (int mt = 0; mt < 6; ++mt) {
#pragma unroll
    for (int i = 0; i < 4; ++i) {
      int c = mt * 16 + (l >> 4) * 4 + i;
      float sc = bn[4 * HD + c], sh = bn[4 * HD + CIN + c];
      size_t idx = (size_t)c * HW + p;
      ob[idx] = acc[mt][i] * sc + sh + xb[idx];
    }
  }
}

// ---------------- launcher ------------------------------------------------
extern "C" void kernel_launch(void* const* d_in, const int* in_sizes, int n_in,
                              void* d_out, int out_size, void* d_ws, size_t ws_size,
                              hipStream_t stream) {
  const float* x   = (const float*)d_in[0];
  const float* w1  = (const float*)d_in[1];
  const float* g1  = (const float*)d_in[2];
  const float* b1  = (const float*)d_in[3];
  const float* m1  = (const float*)d_in[4];
  const float* v1  = (const float*)d_in[5];
  const float* wdw = (const float*)d_in[6];
  const float* gdw = (const float*)d_in[7];
  const float* bdw = (const float*)d_in[8];
  const float* mdw = (const float*)d_in[9];
  const float* vdw = (const float*)d_in[10];
  const float* w2  = (const float*)d_in[11];
  const float* g2  = (const float*)d_in[12];
  const float* b2  = (const float*)d_in[13];
  const float* m2  = (const float*)d_in[14];
  const float* v2  = (const float*)d_in[15];
  float* out = (float*)d_out;

  // workspace layout (needs ~231.5 MB):
  //   h  bf16 [32][576][3136]   115,605,504 B
  //   h2 bf16 [32][576][3136]   115,605,504 B
  //   w1b bf16 [576][96]            110,592 B
  //   w2b bf16 [96][576]            110,592 B
  //   bn  f32  [2496]                 9,984 B
  const size_t HSZ = (size_t)NB * HD * HW;
  char* ws = (char*)d_ws;
  u16*   h   = (u16*)ws;
  u16*   h2  = (u16*)(ws + 2 * HSZ);
  u16*   w1b = (u16*)(ws + 4 * HSZ);
  u16*   w2b = (u16*)(ws + 4 * HSZ + 2 * (size_t)HD * CIN);
  float* bnp = (float*)(ws + 4 * HSZ + 4 * (size_t)HD * CIN);

  prep_kernel<<<dim3((HD * CIN + 255) / 256), 256, 0, stream>>>(
      w1, w2, g1, b1, m1, v1, gdw, bdw, mdw, vdw, g2, b2, m2, v2, w1b, w2b, bnp);

  expand_kernel<<<dim3(7, 9, NB), 256, 0, stream>>>(x, w1b, bnp, h);

  dw_kernel<<<dim3(4, HD, NB), 256, 0, stream>>>(h, wdw, bnp, h2);

  proj_kernel<<<dim3(49, NB), 256, 0, stream>>>(h2, w2b, bnp, x, out);
}

// Round 7
// 249.878 us; speedup vs baseline: 1.4473x; 1.4473x over previous
//
#include <hip/hip_runtime.h>
#include <hip/hip_bf16.h>

typedef __attribute__((ext_vector_type(8))) short bf16x8;
typedef __attribute__((ext_vector_type(4))) float f32x4;
typedef unsigned short u16;
typedef unsigned int u32;

#define EPS 1e-5f
#define CIN 96
#define HD 576
#define HW 3136
#define NB 32

// ---- fused-kernel LDS layout (bytes) ----
// Xt (x tile, [336 px][96 cin] bf16, stride 96) lives at 0, DEAD after xf hoist;
// Hc/H2c overlay it. bnS is disjoint (alive throughout).
#define XTS   96                        // Xt row stride (u16 units)
#define HC_OFF 0
#define HCS   338                       // Hc row stride (u16): even (u32-aligned rows), odd dword stride
#define H2_OFF (64 * HCS * 2)           // 43,264
#define H2S   72                        // H2c row stride (u16): 64 k + 8 pad, 16B aligned
#define BN_OFF (H2_OFF + 224 * H2S * 2) // 75,520 (16B aligned)
#define SMEM_BYTES (BN_OFF + 2496 * 4)  // 85,504

__device__ __forceinline__ u16 f2bf(float f) {
  u32 u = __builtin_bit_cast(u32, f);
  u32 r = u + 0x7fffu + ((u >> 16) & 1u);   // RNE
  return (u16)(r >> 16);
}
__device__ __forceinline__ float bf2f(u16 h) {
  return __builtin_bit_cast(float, (u32)h << 16);
}

// ---------------- kernel 0: weight conversion + BN folding ----------------
__global__ __launch_bounds__(256) void prep_kernel(
    const float* __restrict__ w1, const float* __restrict__ w2,
    const float* __restrict__ g1, const float* __restrict__ b1,
    const float* __restrict__ m1, const float* __restrict__ v1,
    const float* __restrict__ gdw, const float* __restrict__ bdw,
    const float* __restrict__ mdw, const float* __restrict__ vdw,
    const float* __restrict__ g2, const float* __restrict__ b2,
    const float* __restrict__ m2, const float* __restrict__ v2,
    u16* __restrict__ w1b, u16* __restrict__ w2b, float* __restrict__ bn)
{
  int i = blockIdx.x * 256 + threadIdx.x;
  if (i < HD * CIN) {
    w1b[i] = f2bf(w1[i]);
    w2b[i] = f2bf(w2[i]);
  }
  if (i < HD) {
    float s = g1[i] * rsqrtf(v1[i] + EPS);
    bn[i] = s;
    bn[HD + i] = b1[i] - m1[i] * s;
    float sd = gdw[i] * rsqrtf(vdw[i] + EPS);
    bn[2 * HD + i] = sd;
    bn[3 * HD + i] = bdw[i] - mdw[i] * sd;
  }
  if (i < CIN) {
    float s2 = g2[i] * rsqrtf(v2[i] + EPS);
    bn[4 * HD + i] = s2;
    bn[4 * HD + CIN + i] = b2[i] - m2[i] * s2;
  }
}

// ---------------- fused kernel: expand+BN+ReLU -> dw3x3+BN+ReLU -> proj+BN+res
// block = (batch b, 4 output rows r0..r0+3). 448 threads = 7 waves.
// 9 chunks of 64 hd-channels: expand (MFMA, 336 halo px) -> Hc(LDS) ->
// dw (VALU) -> H2c(LDS) -> proj (MFMA, acc in VGPRs). No HBM intermediates.
__global__ __launch_bounds__(448, 2) void fused_kernel(
    const float* __restrict__ x, const u16* __restrict__ w1b,
    const u16* __restrict__ w2b, const float* __restrict__ wdw,
    const float* __restrict__ bnp, float* __restrict__ out)
{
  extern __shared__ __align__(16) char smem[];
  u16*   Xt  = (u16*)(smem);            // [336][XTS]  (dead after xf hoist)
  u16*   Hc  = (u16*)(smem + HC_OFF);   // [64][HCS]
  u16*   H2c = (u16*)(smem + H2_OFF);   // [224][H2S]
  float* bnS = (float*)(smem + BN_OFF); // [2496] same layout as bnp

  const int tid = threadIdx.x;
  const int r0  = blockIdx.x * 4;       // output rows r0..r0+3
  const int b   = blockIdx.y;
  const int l   = tid & 63;
  const int w   = tid >> 6;             // wave 0..6
  const int lr  = l & 15;               // fragment row (M or N index)
  const int kq  = l >> 4;               // 0..3
  const int kb  = kq * 8;               // k sub-offset within 32

  // ---- stage bn (all 2496 floats) + Xt (x tile, transposed, clamped halo)
  for (int i = tid; i < 2496; i += 448) bnS[i] = bnp[i];

  const float* xb = x + (size_t)b * CIN * HW;
  const int pbase = (r0 - 1) * 56;      // global px of halo row 0, col 0
#pragma unroll
  for (int it = 0; it < 9; ++it) {
    int i = it * 448 + tid;             // 0..4031 == 336 px * 12 groups
    int px = i % 336;
    int g  = i / 336;                   // cin group, 8 channels
    int gpx = pbase + px;
    gpx = gpx < 0 ? 0 : (gpx > HW - 1 ? HW - 1 : gpx);   // clamp (masked later)
    const float* xp = xb + (size_t)(g * 8) * HW + gpx;
    bf16x8 pk;
#pragma unroll
    for (int j = 0; j < 8; ++j) pk[j] = (short)f2bf(xp[(size_t)j * HW]);
    *(bf16x8*)&Xt[px * XTS + g * 8] = pk;
  }
  __syncthreads();

  // ---- hoist expand B-fragments (x) into registers; Xt dead afterwards
  bf16x8 xf[3][3];                      // [tile][ks]
#pragma unroll
  for (int t = 0; t < 3; ++t)
#pragma unroll
    for (int ks = 0; ks < 3; ++ks)
      xf[t][ks] = *(const bf16x8*)&Xt[((w * 3 + t) * 16 + lr) * XTS + ks * 32 + kb];
  __syncthreads();                      // Xt reads done before Hc overlays it

  f32x4 pacc[2][6] = {};                // proj accumulator [ntile][mtile]

  for (int kc = 0; kc < 9; ++kc) {
    const int ch0 = kc * 64;
    // ======== expand: M=64 (4 mt), N=336 (3 tiles/wave), K=96 ========
    bf16x8 af[4][3];
#pragma unroll
    for (int mt = 0; mt < 4; ++mt)
#pragma unroll
      for (int ks = 0; ks < 3; ++ks)
        af[mt][ks] = *(const bf16x8*)&w1b[(size_t)(ch0 + mt * 16 + lr) * CIN + ks * 32 + kb];

    // hoist BN1 scale/shift into registers (16B-aligned f32x4 LDS reads);
    // avoids per-t re-loads if alias analysis can't separate bnS from Hc stores
    f32x4 bsc[4], bsh[4];
#pragma unroll
    for (int mt = 0; mt < 4; ++mt) {
      bsc[mt] = *(const f32x4*)&bnS[ch0 + mt * 16 + kq * 4];
      bsh[mt] = *(const f32x4*)&bnS[HD + ch0 + mt * 16 + kq * 4];
    }

#pragma unroll
    for (int t = 0; t < 3; ++t) {
      f32x4 ea[4] = {};
#pragma unroll
      for (int ks = 0; ks < 3; ++ks) {
        ea[0] = __builtin_amdgcn_mfma_f32_16x16x32_bf16(af[0][ks], xf[t][ks], ea[0], 0, 0, 0);
        ea[1] = __builtin_amdgcn_mfma_f32_16x16x32_bf16(af[1][ks], xf[t][ks], ea[1], 0, 0, 0);
        ea[2] = __builtin_amdgcn_mfma_f32_16x16x32_bf16(af[2][ks], xf[t][ks], ea[2], 0, 0, 0);
        ea[3] = __builtin_amdgcn_mfma_f32_16x16x32_bf16(af[3][ks], xf[t][ks], ea[3], 0, 0, 0);
      }
      // epilogue: BN1 + ReLU -> Hc[ch][hpx]
      const int hpx = (w * 3 + t) * 16 + lr;
#pragma unroll
      for (int mt = 0; mt < 4; ++mt)
#pragma unroll
        for (int i = 0; i < 4; ++i) {
          int chl = mt * 16 + kq * 4 + i;
          float v = fmaxf(ea[mt][i] * bsc[mt][i] + bsh[mt][i], 0.f);
          Hc[chl * HCS + hpx] = f2bf(v);
        }
    }
    __syncthreads();                    // Hc ready; prev H2c proj-reads drained

    // ======== dw 3x3: 896 items = 64 ch x 14 col-groups ========
#pragma unroll
    for (int it = 0; it < 2; ++it) {
      int t   = it * 448 + tid;         // 0..895
      int chl = t & 63;
      int cg  = t >> 6;                 // 0..13
      int c0  = cg * 4;
      int gch = ch0 + chl;
      float wk[9];
#pragma unroll
      for (int k = 0; k < 9; ++k) wk[k] = wdw[gch * 9 + k];
      const float sdw = bnS[2 * HD + gch], hdw = bnS[3 * HD + gch];

      float win[6][8];
#pragma unroll
      for (int hr = 0; hr < 6; ++hr) {
        int grow = r0 - 1 + hr;
        bool rv = (grow >= 0) && (grow < 56);
        const u16* rp = &Hc[chl * HCS + hr * 56];
#pragma unroll
        for (int k2 = 0; k2 < 4; ++k2) {
          int cb = c0 - 2 + k2 * 2;     // -2..56 (even); in-row pad covers cb=56
          u32 pr = (rv && cb >= 0) ? *(const u32*)(rp + cb) : 0u;
          win[hr][k2 * 2]     = bf2f((u16)pr);
          win[hr][k2 * 2 + 1] = bf2f((u16)(pr >> 16));
        }
        if (c0 + 4 >= 56) win[hr][6] = 0.f;   // right-edge col 56
      }
#pragma unroll
      for (int orr = 0; orr < 4; ++orr) {
        float a4[4] = {0.f, 0.f, 0.f, 0.f};
#pragma unroll
        for (int dy = 0; dy < 3; ++dy)
#pragma unroll
          for (int j = 0; j < 4; ++j)
#pragma unroll
            for (int dx = 0; dx < 3; ++dx)
              a4[j] += wk[dy * 3 + dx] * win[orr + dy][j + dx + 1];
#pragma unroll
        for (int j = 0; j < 4; ++j) {
          float v = fmaxf(a4[j] * sdw + hdw, 0.f);
          H2c[(orr * 56 + c0 + j) * H2S + chl] = f2bf(v);
        }
      }
    }
    __syncthreads();                    // H2c ready; Hc reads drained

    // ======== proj accumulate: M=96 (6 mt), N: tiles {2w,2w+1}, K=64 ========
    bf16x8 pa[6][2];
#pragma unroll
    for (int mt = 0; mt < 6; ++mt)
#pragma unroll
      for (int ks = 0; ks < 2; ++ks)
        pa[mt][ks] = *(const bf16x8*)&w2b[(size_t)(mt * 16 + lr) * HD + ch0 + ks * 32 + kb];
#pragma unroll
    for (int ntl = 0; ntl < 2; ++ntl) {
      int pt = w * 2 + ntl;
      bf16x8 pb[2];
#pragma unroll
      for (int ks = 0; ks < 2; ++ks)
        pb[ks] = *(const bf16x8*)&H2c[(pt * 16 + lr) * H2S + ks * 32 + kb];
#pragma unroll
      for (int ks = 0; ks < 2; ++ks)
#pragma unroll
        for (int mt = 0; mt < 6; ++mt)
          pacc[ntl][mt] = __builtin_amdgcn_mfma_f32_16x16x32_bf16(pa[mt][ks], pb[ks], pacc[ntl][mt], 0, 0, 0);
    }
  }

  // ---- final epilogue: BN2 + residual, fp32 out
  const float* xr = x   + (size_t)b * CIN * HW + r0 * 56;
  float*       ob = out + (size_t)b * CIN * HW + r0 * 56;
#pragma unroll
  for (int ntl = 0; ntl < 2; ++ntl) {
    int opx = (w * 2 + ntl) * 16 + lr;
#pragma unroll
    for (int mt = 0; mt < 6; ++mt)
#pragma unroll
      for (int i = 0; i < 4; ++i) {
        int c = mt * 16 + kq * 4 + i;
        float v = pacc[ntl][mt][i] * bnS[4 * HD + c] + bnS[4 * HD + CIN + c];
        size_t idx = (size_t)c * HW + opx;
        ob[idx] = v + xr[idx];
      }
  }
}

// ---------------- launcher ------------------------------------------------
extern "C" void kernel_launch(void* const* d_in, const int* in_sizes, int n_in,
                              void* d_out, int out_size, void* d_ws, size_t ws_size,
                              hipStream_t stream) {
  const float* x   = (const float*)d_in[0];
  const float* w1  = (const float*)d_in[1];
  const float* g1  = (const float*)d_in[2];
  const float* b1  = (const float*)d_in[3];
  const float* m1  = (const float*)d_in[4];
  const float* v1  = (const float*)d_in[5];
  const float* wdw = (const float*)d_in[6];
  const float* gdw = (const float*)d_in[7];
  const float* bdw = (const float*)d_in[8];
  const float* mdw = (const float*)d_in[9];
  const float* vdw = (const float*)d_in[10];
  const float* w2  = (const float*)d_in[11];
  const float* g2  = (const float*)d_in[12];
  const float* b2  = (const float*)d_in[13];
  const float* m2  = (const float*)d_in[14];
  const float* v2  = (const float*)d_in[15];
  float* out = (float*)d_out;

  // workspace: w1b bf16 [576][96], w2b bf16 [96][576], bn f32 [2496]  (~231 KB)
  char* ws = (char*)d_ws;
  u16*   w1b = (u16*)ws;
  u16*   w2b = (u16*)(ws + 2 * (size_t)HD * CIN);
  float* bnp = (float*)(ws + 4 * (size_t)HD * CIN);

  (void)hipFuncSetAttribute((const void*)fused_kernel,
                            hipFuncAttributeMaxDynamicSharedMemorySize, SMEM_BYTES);

  prep_kernel<<<dim3((HD * CIN + 255) / 256), 256, 0, stream>>>(
      w1, w2, g1, b1, m1, v1, gdw, bdw, mdw, vdw, g2, b2, m2, v2, w1b, w2b, bnp);

  fused_kernel<<<dim3(14, NB), 448, SMEM_BYTES, stream>>>(x, w1b, w2b, wdw, bnp, out);
}